// Round 9
// baseline (230.426 us; speedup 1.0000x reference)
//
#include <hip/hip_runtime.h>
#include <hip/hip_bf16.h>

#define DD 128
#define TM 64
#define LD 136        // padded LDS row stride (bf16 elems)
#define SB 128        // scan blocks
#define GRID_MLP 1024 // 4 blocks/CU persistent

typedef short bf16x8 __attribute__((ext_vector_type(8)));
typedef float f32x4  __attribute__((ext_vector_type(4)));

__device__ __forceinline__ unsigned short f2bf(float f) {
  unsigned int u = __float_as_uint(f);
  u += 0x7FFFu + ((u >> 16) & 1u);   // RNE
  return (unsigned short)(u >> 16);
}
__device__ __forceinline__ unsigned int pack2(float lo, float hi) {
  return (unsigned int)f2bf(lo) | ((unsigned int)f2bf(hi) << 16);
}
__device__ __forceinline__ float bf2f(unsigned short u) {
  union { unsigned int i; float f; } x; x.i = ((unsigned int)u) << 16; return x.f;
}
// unpack one dword (2 bf16) to two fp32 and add into a[2]
__device__ __forceinline__ void add2(float* a, unsigned int w) {
  union { unsigned int i; float f; } lo, hi;
  lo.i = w << 16; hi.i = w & 0xFFFF0000u;
  a[0] += lo.f; a[1] += hi.f;
}

// init: zero cnt, convert weights AND features fp32->bf16. One dispatch.
__global__ __launch_bounds__(256) void k_init(const float* __restrict__ w1,
                                              const float* __restrict__ w2,
                                              const float* __restrict__ feat,
                                              unsigned short* __restrict__ wbf1,
                                              unsigned short* __restrict__ wbf2,
                                              unsigned short* __restrict__ featbf,
                                              int* __restrict__ cnt, int nrows) {
  int i0 = blockIdx.x * 256 + threadIdx.x;
  int GT = gridDim.x * 256;
  for (int i = i0; i < nrows; i += GT) cnt[i] = 0;
  for (int i = i0; i < DD * DD; i += GT) { wbf1[i] = f2bf(w1[i]); wbf2[i] = f2bf(w2[i]); }
  int total8 = nrows * 16;   // 8 elems per thread
  for (int i = i0; i < total8; i += GT) {
    const float* fp = feat + (long long)i * 8;
    float4 a = *reinterpret_cast<const float4*>(fp);
    float4 b = *reinterpret_cast<const float4*>(fp + 4);
    uint4 u;
    u.x = pack2(a.x, a.y); u.y = pack2(a.z, a.w);
    u.z = pack2(b.x, b.y); u.w = pack2(b.z, b.w);
    *reinterpret_cast<uint4*>(featbf + (long long)i * 8) = u;
  }
}

// cnt[dst]++ per edge (int atomics, L2-resident)
__global__ __launch_bounds__(256) void k_hist(const int* __restrict__ ei, int* __restrict__ cnt,
                                              int ne) {
  int e = blockIdx.x * 256 + threadIdx.x;
  if (e < ne) atomicAdd(&cnt[ei[ne + e]], 1);
}

// scan stage 1: per-block chunk sums
__global__ __launch_bounds__(256) void k_scan1(const int* __restrict__ cnt,
                                               int* __restrict__ bsum, int n) {
  __shared__ int red[256];
  int b = blockIdx.x, t = threadIdx.x;
  int chunk = (n + SB - 1) / SB;
  int lo = b * chunk, hi = min(n, lo + chunk);
  int s = 0;
  for (int i = lo + t; i < hi; i += 256) s += cnt[i];
  red[t] = s;
  __syncthreads();
  for (int off = 128; off; off >>= 1) {
    if (t < off) red[t] += red[t + off];
    __syncthreads();
  }
  if (t == 0) bsum[b] = red[0];
}

// scan stage 2: each block redundantly scans bsum[SB] in LDS (folds old k_scan2),
// then exclusive-scans its chunk -> ofs, cur.
__global__ __launch_bounds__(256) void k_scan3(const int* __restrict__ cnt,
                                               const int* __restrict__ bsum,
                                               int* __restrict__ ofs, int* __restrict__ cur,
                                               int n) {
  __shared__ int red[256];
  __shared__ int sbs[SB];
  int b = blockIdx.x, t = threadIdx.x;

  int ov = (t < SB) ? bsum[t] : 0;
  if (t < SB) sbs[t] = ov;
  __syncthreads();
  for (int off = 1; off < SB; off <<= 1) {
    int v = (t < SB && t >= off) ? sbs[t - off] : 0;
    __syncthreads();
    if (t < SB) sbs[t] += v;
    __syncthreads();
  }
  if (t < SB) sbs[t] -= ov;   // exclusive
  __syncthreads();
  int base = sbs[b];
  if (b == SB - 1 && t == SB - 1) ofs[n] = sbs[t] + ov;  // total

  int chunk  = (n + SB - 1) / SB;
  int tchunk = (chunk + 255) / 256;
  int blo = b * chunk, bhi = min(n, blo + chunk);
  int lo = blo + t * tchunk, hi = min(bhi, lo + tchunk);
  int s = 0;
  for (int i = lo; i < hi; ++i) s += cnt[i];
  int mine = s;
  red[t] = s;
  __syncthreads();
  for (int off = 1; off < 256; off <<= 1) {
    int v = (t >= off) ? red[t - off] : 0;
    __syncthreads();
    red[t] += v;
    __syncthreads();
  }
  int run = base + red[t] - mine;
  for (int i = lo; i < hi; ++i) {
    int c = cnt[i];
    ofs[i] = run; cur[i] = run;
    run += c;
  }
}

// csr[pos] = src, pos = cur[dst]++
__global__ __launch_bounds__(256) void k_fill(const int* __restrict__ ei, int* __restrict__ cur,
                                              int* __restrict__ csr, int ne) {
  int e = blockIdx.x * 256 + threadIdx.x;
  if (e >= ne) return;
  int pos = atomicAdd(&cur[ei[ne + e]], 1);
  csr[pos] = ei[e];
}

// Gather from bf16 features (256 B/row): h = feat[row] + sum(neighbors).
// fp32 accumulation of bf16-rounded inputs; RNE-pack to bf16 agg (== hbuf).
// Halves gather demand vs fp32 (258 -> ~130 MB).
__global__ __launch_bounds__(256) void k_agg(
    const unsigned short* __restrict__ featbf, const int* __restrict__ ofs,
    const int* __restrict__ csr, unsigned short* __restrict__ agg, int nrows)
{
  int t = blockIdx.x * 256 + threadIdx.x;   // 16 threads per row, 8 cols each
  int row = t >> 4;
  if (row >= nrows) return;
  int c = (t & 15) * 8;

  float a[8];
  {
    uint4 u = *reinterpret_cast<const uint4*>(featbf + (long long)row * DD + c);
    union { unsigned int i; float f; } x;
    x.i = u.x << 16; a[0] = x.f;  x.i = u.x & 0xFFFF0000u; a[1] = x.f;
    x.i = u.y << 16; a[2] = x.f;  x.i = u.y & 0xFFFF0000u; a[3] = x.f;
    x.i = u.z << 16; a[4] = x.f;  x.i = u.z & 0xFFFF0000u; a[5] = x.f;
    x.i = u.w << 16; a[6] = x.f;  x.i = u.w & 0xFFFF0000u; a[7] = x.f;
  }

  int o0 = ofs[row], o1 = ofs[row + 1];
  int j = o0;
  // 4 independent loads in flight per iteration
  for (; j + 4 <= o1; j += 4) {
    uint4 u0 = *reinterpret_cast<const uint4*>(featbf + (long long)csr[j]     * DD + c);
    uint4 u1 = *reinterpret_cast<const uint4*>(featbf + (long long)csr[j + 1] * DD + c);
    uint4 u2 = *reinterpret_cast<const uint4*>(featbf + (long long)csr[j + 2] * DD + c);
    uint4 u3 = *reinterpret_cast<const uint4*>(featbf + (long long)csr[j + 3] * DD + c);
    add2(a + 0, u0.x); add2(a + 2, u0.y); add2(a + 4, u0.z); add2(a + 6, u0.w);
    add2(a + 0, u1.x); add2(a + 2, u1.y); add2(a + 4, u1.z); add2(a + 6, u1.w);
    add2(a + 0, u2.x); add2(a + 2, u2.y); add2(a + 4, u2.z); add2(a + 6, u2.w);
    add2(a + 0, u3.x); add2(a + 2, u3.y); add2(a + 4, u3.z); add2(a + 6, u3.w);
  }
  for (; j < o1; ++j) {
    uint4 u0 = *reinterpret_cast<const uint4*>(featbf + (long long)csr[j] * DD + c);
    add2(a + 0, u0.x); add2(a + 2, u0.y); add2(a + 4, u0.z); add2(a + 6, u0.w);
  }

  uint4 u;
  u.x = pack2(a[0], a[1]); u.y = pack2(a[2], a[3]);
  u.z = pack2(a[4], a[5]); u.w = pack2(a[6], a[7]);
  *reinterpret_cast<uint4*>(agg + (long long)row * DD + c) = u;
}

// Persistent fused MLP. Row-major bf16 hbuf == MFMA A-fragment layout, so GEMM1
// loads A directly from global (fully-sectored 16B/lane loads) — no LDS staging,
// 2 barriers/tile. h2 transits LDS; epilogue packs via LDS for coalesced stores.
// BN stats register-accumulated per block (no device-scope sync — R4/R5 lesson).
__global__ __launch_bounds__(256) void k_mlp(
    unsigned short* hb,
    const unsigned short* __restrict__ wbf1, const float* __restrict__ b1,
    const unsigned short* __restrict__ wbf2, const float* __restrict__ b2,
    float* __restrict__ partial, int nrows, int ntiles)
{
  __shared__ unsigned short ldsP[TM * LD];   // epilogue pack buffer
  __shared__ unsigned short ldsH2[TM * LD];  // h2 buffer
  const int tid  = threadIdx.x;
  const int wave = tid >> 6, lane = tid & 63;
  const int q = lane >> 4, l16 = lane & 15;
  const int col0 = wave * 32;

  bf16x8 bw1[2][4], bw2[2][4];
  float bias1[2], bias2[2];
  for (int n = 0; n < 2; ++n) {
    int jc = col0 + n * 16 + l16;
    bias1[n] = b1[jc];
    bias2[n] = b2[jc];
    for (int kk = 0; kk < 4; ++kk) {
      bw1[n][kk] = *reinterpret_cast<const bf16x8*>(wbf1 + jc * DD + kk * 32 + q * 8);
      bw2[n][kk] = *reinterpret_cast<const bf16x8*>(wbf2 + jc * DD + kk * 32 + q * 8);
    }
  }

  const bf16x8 zf = {0, 0, 0, 0, 0, 0, 0, 0};
  float fs[2] = {0.f, 0.f}, fs2[2] = {0.f, 0.f};

  for (int tile = blockIdx.x; tile < ntiles; tile += GRID_MLP) {
    const int row0 = tile * TM;

    f32x4 acc[4][2];
    const f32x4 zero = {0.f, 0.f, 0.f, 0.f};
    for (int m = 0; m < 4; ++m) for (int n = 0; n < 2; ++n) acc[m][n] = zero;

    // GEMM1: A-fragments straight from global (row-major == fragment layout).
    #pragma unroll
    for (int kk = 0; kk < 4; ++kk) {
      bf16x8 aF[4];
      #pragma unroll
      for (int m = 0; m < 4; ++m) {
        int row = row0 + m * 16 + l16;
        aF[m] = (row < nrows)
            ? *reinterpret_cast<const bf16x8*>(hb + (long long)row * DD + kk * 32 + q * 8)
            : zf;
      }
      #pragma unroll
      for (int m = 0; m < 4; ++m)
        #pragma unroll
        for (int n = 0; n < 2; ++n)
          acc[m][n] = __builtin_amdgcn_mfma_f32_16x16x32_bf16(aF[m], bw1[n][kk], acc[m][n], 0, 0, 0);
    }

    // h2 = relu(acc + b1) -> ldsH2 (C/D: col=lane&15, row=quad*4+reg)
    for (int m = 0; m < 4; ++m)
      for (int n = 0; n < 2; ++n)
        for (int r = 0; r < 4; ++r) {
          float v = fmaxf(acc[m][n][r] + bias1[n], 0.f);
          ldsH2[(m * 16 + q * 4 + r) * LD + (col0 + n * 16 + l16)] = f2bf(v);
        }
    __syncthreads();   // S1: h2 visible; also protects ldsP reuse vs prev store

    for (int m = 0; m < 4; ++m) for (int n = 0; n < 2; ++n) acc[m][n] = zero;

    // GEMM2 from LDS
    #pragma unroll
    for (int kk = 0; kk < 4; ++kk) {
      bf16x8 aF[4];
      #pragma unroll
      for (int m = 0; m < 4; ++m)
        aF[m] = *reinterpret_cast<const bf16x8*>(&ldsH2[(m * 16 + l16) * LD + kk * 32 + q * 8]);
      #pragma unroll
      for (int m = 0; m < 4; ++m)
        #pragma unroll
        for (int n = 0; n < 2; ++n)
          acc[m][n] = __builtin_amdgcn_mfma_f32_16x16x32_bf16(aF[m], bw2[n][kk], acc[m][n], 0, 0, 0);
    }

    // Epilogue: relu+bias, accumulate BN stats in registers, pack bf16 -> ldsP.
    for (int m = 0; m < 4; ++m)
      for (int n = 0; n < 2; ++n) {
        int col = col0 + n * 16 + l16;
        for (int r = 0; r < 4; ++r) {
          int rl = m * 16 + q * 4 + r;
          float v = fmaxf(acc[m][n][r] + bias2[n], 0.f);
          ldsP[rl * LD + col] = f2bf(v);
          if (row0 + rl < nrows) { fs[n] += v; fs2[n] += v * v; }
        }
      }
    __syncthreads();   // S2: pack visible; also protects ldsH2 reuse vs next h2

    // Coalesced bf16 store of the tile back to hb (in-place over agg rows).
    for (int it = 0; it < 4; ++it) {
      int idx = it * 2048 + tid * 8;
      int r = idx >> 7, c = idx & 127;
      int row = row0 + r;
      if (row < nrows)
        *reinterpret_cast<uint4*>(hb + (long long)row * DD + c) =
            *reinterpret_cast<const uint4*>(&ldsP[r * LD + c]);
    }
  }

  // per-block partial store (non-atomic)
  for (int off = 16; off < 64; off <<= 1)
    for (int n = 0; n < 2; ++n) {
      fs[n]  += __shfl_xor(fs[n], off);
      fs2[n] += __shfl_xor(fs2[n], off);
    }
  if (q == 0) {
    float* pb = partial + (long long)blockIdx.x * 256;
    for (int n = 0; n < 2; ++n) {
      int col = col0 + n * 16 + l16;
      pb[col]       = fs[n];
      pb[128 + col] = fs2[n];
    }
  }
}

// Reduce per-block partials -> scale/shift. 128 blocks: block c owns columns
// (c, 128+c).
__global__ __launch_bounds__(256) void k_stats(const float* __restrict__ partial,
                                               const float* __restrict__ gamma,
                                               const float* __restrict__ beta,
                                               float* __restrict__ scsh, int nrows) {
  __shared__ float s0[256], s1[256];
  int c = blockIdx.x;   // 0..127
  int t = threadIdx.x;
  float a = 0.f, b = 0.f;
  for (int r = t; r < GRID_MLP; r += 256) {
    a += partial[(long long)r * 256 + c];
    b += partial[(long long)r * 256 + 128 + c];
  }
  s0[t] = a; s1[t] = b;
  __syncthreads();
  for (int off = 128; off; off >>= 1) {
    if (t < off) { s0[t] += s0[t + off]; s1[t] += s1[t + off]; }
    __syncthreads();
  }
  if (t == 0) {
    float mean = s0[0] / (float)nrows;
    float var  = fmaxf(s1[0] / (float)nrows - mean * mean, 0.f);
    float inv  = rsqrtf(var + 1e-5f);
    float sc   = gamma[c] * inv;
    scsh[c]       = sc;
    scsh[128 + c] = beta[c] - mean * sc;
  }
}

// BN apply: read bf16 hbuf (L3-warm), write fp32 out. One thread per 8 elems.
__global__ __launch_bounds__(256) void k_bn(const unsigned short* __restrict__ hbuf,
                                            float* __restrict__ out,
                                            const float* __restrict__ scsh,
                                            long long total8) {
  long long t = (long long)blockIdx.x * 256 + threadIdx.x;
  if (t >= total8) return;
  int c0 = (int)((t * 8) & 127);
  float4 sa = *reinterpret_cast<const float4*>(scsh + c0);
  float4 sb = *reinterpret_cast<const float4*>(scsh + c0 + 4);
  float4 ha = *reinterpret_cast<const float4*>(scsh + 128 + c0);
  float4 hb = *reinterpret_cast<const float4*>(scsh + 132 + c0);
  uint4 u = *reinterpret_cast<const uint4*>(hbuf + t * 8);
  float4 a, b;
  a.x = bf2f((unsigned short)(u.x & 0xFFFF)) * sa.x + ha.x;
  a.y = bf2f((unsigned short)(u.x >> 16))    * sa.y + ha.y;
  a.z = bf2f((unsigned short)(u.y & 0xFFFF)) * sa.z + ha.z;
  a.w = bf2f((unsigned short)(u.y >> 16))    * sa.w + ha.w;
  b.x = bf2f((unsigned short)(u.z & 0xFFFF)) * sb.x + hb.x;
  b.y = bf2f((unsigned short)(u.z >> 16))    * sb.y + hb.y;
  b.z = bf2f((unsigned short)(u.w & 0xFFFF)) * sb.z + hb.z;
  b.w = bf2f((unsigned short)(u.w >> 16))    * sb.w + hb.w;
  float* of = out + t * 8;
  *reinterpret_cast<float4*>(of)     = a;
  *reinterpret_cast<float4*>(of + 4) = b;
}

extern "C" void kernel_launch(void* const* d_in, const int* in_sizes, int n_in,
                              void* d_out, int out_size, void* d_ws, size_t ws_size,
                              hipStream_t stream) {
  const float* feat  = (const float*)d_in[0];
  const int*   eidx  = (const int*)d_in[1];
  const float* w1    = (const float*)d_in[2];
  const float* b1    = (const float*)d_in[3];
  const float* w2    = (const float*)d_in[4];
  const float* b2    = (const float*)d_in[5];
  const float* gamma = (const float*)d_in[6];
  const float* beta  = (const float*)d_in[7];
  float* out = (float*)d_out;

  const int nrows  = in_sizes[0] / DD;       // 100000
  const int ne     = in_sizes[1] / 2;        // 400000
  const int ntiles = (nrows + TM - 1) / TM;  // 1563

  // ws layout (4B words), featbf + hbuf last (16B-aligned by construction):
  int* base = (int*)d_ws;
  unsigned short* wbf1 = (unsigned short*)base;            // 16384 bf16
  unsigned short* wbf2 = (unsigned short*)(base + 8192);   // 16384 bf16
  float* scsh  = (float*)(base + 16384);                   // 256
  int*   ofs   = base + 16384 + 256;                       // nrows+1
  int*   cur   = ofs + (nrows + 1);
  int*   csr   = cur + nrows;
  int*   bsum  = csr + ne;                                 // SB
  float* partial = (float*)(bsum + SB);                    // GRID_MLP*256 (1 MB)
  int*   cnt   = (int*)(partial + (size_t)GRID_MLP * 256); // nrows
  long long w_off = (long long)(cnt + nrows - base);
  w_off = (w_off + 3) & ~3LL;                              // 16B align
  unsigned short* featbf = (unsigned short*)(base + w_off);       // nrows*DD bf16 (25.6 MB)
  unsigned short* hbuf   = featbf + (long long)nrows * DD;        // nrows*DD bf16 (25.6 MB)

  const long long total8 = (long long)nrows * DD / 8;      // 1.6M
  const int agg_blocks  = (nrows * 16 + 255) / 256;        // 6250

  k_init <<<2048,                         256, 0, stream>>>(w1, w2, feat, wbf1, wbf2,
                                                            featbf, cnt, nrows);
  k_hist <<<(ne + 255) / 256,             256, 0, stream>>>(eidx, cnt, ne);
  k_scan1<<<SB,                           256, 0, stream>>>(cnt, bsum, nrows);
  k_scan3<<<SB,                           256, 0, stream>>>(cnt, bsum, ofs, cur, nrows);
  k_fill <<<(ne + 255) / 256,             256, 0, stream>>>(eidx, cur, csr, ne);
  k_agg  <<<agg_blocks,                   256, 0, stream>>>(featbf, ofs, csr, hbuf, nrows);
  k_mlp  <<<GRID_MLP,                     256, 0, stream>>>(hbuf, wbf1, b1, wbf2, b2,
                                                            partial, nrows, ntiles);
  k_stats<<<128,                          256, 0, stream>>>(partial, gamma, beta, scsh, nrows);
  k_bn   <<<(int)((total8 + 255) / 256),  256, 0, stream>>>(hbuf, out, scsh, total8);
}